// Round 16
// baseline (454.474 us; speedup 1.0000x reference)
//
#include <hip/hip_runtime.h>
#include <hip/hip_bf16.h>
#include <math.h>

#define TOK   4096
#define DIM   1024
#define DMLP  4096
#define NE    8
#define BM    128
#define BN    128
#define BN2   64
#define BK    128
#define PADMAX (TOK + NE * BM)   // 5120 padded slots
#define NTILES (PADMAX / BM)     // 40 row-tiles
#define EPAD  136                // epilogue LDS row stride (shorts), 16B-aligned

typedef __attribute__((ext_vector_type(8))) short  short8;
typedef __attribute__((ext_vector_type(4))) float  float4v;
typedef __attribute__((ext_vector_type(4))) unsigned short ushort4v;
typedef __attribute__((ext_vector_type(2))) unsigned long long ull2;

// async global->LDS, 16 B per lane; LDS dest is wave-uniform base + lane*16;
// GLOBAL source address is per-lane (enables the perm-gather A staging).
#define ASYNC16(gp, lp) __builtin_amdgcn_global_load_lds( \
    (const __attribute__((address_space(1))) unsigned int*)(gp), \
    (__attribute__((address_space(3))) unsigned int*)(lp), 16, 0, 0)

// A-side LDS layout (row-major, swizzled): BK=128 -> 16 granules/row
#define SWZ(R, C) (((C) & 8) | (((C) ^ (R)) & 7))
#define FRAG_OFF(R, C) ((((R) << 4) + SWZ(R, C)) << 3)
// B-side LDS layout (granule-major): [C][n][8], offset in shorts (n<128)
#define BOFF(C, n) ((((C) << 7) + (n)) << 3)

static __device__ __forceinline__ unsigned short f2bf(float f) {
  unsigned u = __float_as_uint(f);
  u += 0x7fffu + ((u >> 16) & 1u);
  return (unsigned short)(u >> 16);
}

// exact-erf GELU via Abramowitz&Stegun 7.1.26 (|err| < 1.5e-7)
static __device__ __forceinline__ float gelu_erf(float v) {
  const float x = fabsf(v) * 0.70710678118654752f;
  const float t = __builtin_amdgcn_rcpf(1.0f + 0.3275911f * x);
  const float poly = ((((1.061405429f * t - 1.453152027f) * t + 1.421413741f) * t
                       - 0.284496736f) * t + 0.254829592f) * t;
  const float erf_abs = 1.0f - poly * __expf(-x * x);
  return 0.5f * v * (1.0f + copysignf(erf_abs, v));
}

// ---------------------------------------------------------------------------
// group body (single block): token counts -> expert offsets -> perm/tile_e.
// ---------------------------------------------------------------------------
static __device__ __forceinline__
void group_body(const int* __restrict__ eidx, int* __restrict__ perm,
                int* __restrict__ tile_e, int tid) {
  __shared__ int cnt[NE], off[NE], len[NE], cur[NE];
  if (tid < NE) cnt[tid] = 0;
  __syncthreads();
  for (int i = tid; i < TOK; i += 256) atomicAdd(&cnt[eidx[i]], 1);
  __syncthreads();
  if (tid == 0) {
    int o = 0;
    for (int e = 0; e < NE; e++) {
      off[e] = o;
      len[e] = ((cnt[e] + BM - 1) / BM) * BM;
      cur[e] = o;
      o += len[e];
    }
  }
  __syncthreads();
  for (int s = tid; s < PADMAX; s += 256) perm[s] = -1;
  __syncthreads();
  for (int i = tid; i < TOK; i += 256) {
    const int e = eidx[i];
    const int p = atomicAdd(&cur[e], 1);
    perm[p] = i;
  }
  __syncthreads();
  for (int t = tid; t < NTILES; t += 256) {
    const int row = t * BM;
    int te = -1;
    for (int e = 0; e < NE; e++)
      if (row >= off[e] && row < off[e] + len[e]) te = e;
    tile_e[t] = te;
  }
}

// ---------------------------------------------------------------------------
// convpack body (r9 proven): W [K][N] f32 -> WT [K/8][N][8] bf16.
// ---------------------------------------------------------------------------
static __device__ __forceinline__
void convpack_body(const float* __restrict__ W, unsigned short* __restrict__ WT,
                   int K, int N, int kg, int nblk, int e, int tid) {
  const int n0 = nblk * 1024 + tid * 4;
  const float* Win = W + (size_t)e * K * N + (size_t)kg * 8 * N + n0;
  unsigned short* Wout = WT + (size_t)e * K * N + ((size_t)kg * N + n0) * 8;
  float4v v[8];
#pragma unroll
  for (int j = 0; j < 8; j++) v[j] = *(const float4v*)(Win + (size_t)j * N);
#pragma unroll
  for (int q = 0; q < 4; q++) {
    short8 g;
#pragma unroll
    for (int j = 0; j < 8; j++) g[j] = (short)f2bf(v[j][q]);
    *(short8*)(Wout + q * 8) = g;
  }
}

// ---------------------------------------------------------------------------
// Kernel 1 (prep): group (block 0) + convpack(W1) + x f32->bf16 TOKEN-ORDER
// + out bias-init (out[i] = b2[eidx[i]], enables gemm2 split-K atomics).
// Blocks: [0]=group, [1,4097)=W1 conv, [4097,8193)=x rows.
// ---------------------------------------------------------------------------
__global__ __launch_bounds__(256)
void prep_kernel(const int* __restrict__ eidx, int* __restrict__ perm,
                 int* __restrict__ tile_e,
                 const float* __restrict__ W1, unsigned short* __restrict__ W1T,
                 const float* __restrict__ x, unsigned short* __restrict__ xbf,
                 const float* __restrict__ b2, float* __restrict__ out) {
  const int bid = blockIdx.x;
  const int tid = threadIdx.x;
  if (bid == 0) {
    group_body(eidx, perm, tile_e, tid);
  } else if (bid < 4097) {
    const int b = bid - 1;
    convpack_body(W1, W1T, DIM, DMLP, b & 127, (b >> 7) & 3, b >> 9, tid);
  } else {
    const int row = bid - 4097;           // 0..4095, token order
    const float4v v = *(const float4v*)(x + (size_t)row * DIM + tid * 4);
    ushort4v o;
#pragma unroll
    for (int q = 0; q < 4; q++) o[q] = f2bf(v[q]);
    *(ushort4v*)(xbf + (size_t)row * DIM + tid * 4) = o;
    // bias-init: out[row] = b2[expert(row)]
    const int e = eidx[row];
    const float4v bb = *(const float4v*)(b2 + (size_t)e * DIM + tid * 4);
    *(float4v*)(out + (size_t)row * DIM + tid * 4) = bb;
  }
}

// ---------------------------------------------------------------------------
// Kernel 2: h = gelu(x[perm] @ W1 + b1) -> bf16. 128x128 tile, BK=128.
// A staged directly from token-ordered xbf via per-lane perm-gathered global
// addresses. B granule-major. Padded epilogue restage. + W2 conv tail work.
// Grid: (DMLP/BN, NTILES) col-fastest. (r15 exact)
// ---------------------------------------------------------------------------
__global__ __launch_bounds__(256)
void gemm1_kernel(const unsigned short* __restrict__ xbf,
                  const unsigned short* __restrict__ W1T,
                  const float* __restrict__ b1, const int* __restrict__ perm,
                  const int* __restrict__ tile_e,
                  unsigned short* __restrict__ h,
                  const float* __restrict__ W2, unsigned short* __restrict__ W2T) {
  const int bt = blockIdx.y;                 // row tile
  const int te = tile_e[bt];
  const int n0 = blockIdx.x * BN;            // col tile
  const int tid = threadIdx.x;

  __shared__ __align__(16) unsigned short SMEM[2 * BM * BK];

  if (te >= 0) {
    const unsigned short* Bsrc = W1T + (size_t)te * DIM * DMLP + (size_t)n0 * 8;

    const int rr = tid >> 4, q = tid & 15;
    const int cs = SWZ(rr, q);
    const unsigned short* aP[8];
#pragma unroll
    for (int t = 0; t < 8; t++) {
      const int tok = perm[bt * BM + 16 * t + rr];
      aP[t] = xbf + (size_t)(tok < 0 ? 0 : tok) * DIM + cs * 8;
    }
    const int bC = tid >> 7, bn = tid & 127;   // t adds 2 to C per step
    const unsigned short* b0 = Bsrc + ((size_t)bC * DMLP + bn) * 8;

    const int wid = tid >> 6, lane = tid & 63;
    const int wm = (wid >> 1) * 64, wn = (wid & 1) * 64;
    const int l15 = lane & 15, quad = lane >> 4;

    float4v acc[4][4];
#pragma unroll
    for (int i = 0; i < 4; i++)
#pragma unroll
      for (int j = 0; j < 4; j++) acc[i][j] = (float4v){0.f, 0.f, 0.f, 0.f};

    for (int k0 = 0; k0 < DIM; k0 += BK) {
      const int kg0 = k0 >> 3;
#pragma unroll
      for (int t = 0; t < 8; t++)
        ASYNC16(aP[t] + k0, &SMEM[(t * 256 + tid) * 8]);
#pragma unroll
      for (int t = 0; t < 8; t++)
        ASYNC16(b0 + (size_t)(kg0 + 2 * t) * DMLP * 8,
                &SMEM[BM * BK + (t * 256 + tid) * 8]);
      __syncthreads();

#pragma unroll
      for (int hh = 0; hh < 4; hh++) {
        short8 a[4], b[4];
        const int C = hh * 4 + quad;
#pragma unroll
        for (int i = 0; i < 4; i++)
          a[i] = *(const short8*)&SMEM[FRAG_OFF(wm + i * 16 + l15, C)];
#pragma unroll
        for (int j = 0; j < 4; j++)
          b[j] = *(const short8*)&SMEM[BM * BK + BOFF(C, wn + j * 16 + l15)];
#pragma unroll
        for (int i = 0; i < 4; i++)
#pragma unroll
          for (int j = 0; j < 4; j++)
            acc[i][j] = __builtin_amdgcn_mfma_f32_16x16x32_bf16(a[i], b[j], acc[i][j], 0, 0, 0);
      }
      __syncthreads();
    }

    // ---- epilogue: gelu -> bf16 into padded LDS tile, then wide stores ----
#pragma unroll
    for (int i = 0; i < 4; i++) {
#pragma unroll
      for (int j = 0; j < 4; j++) {
        const int colL = wn + j * 16 + l15;
        const float bias = b1[te * DMLP + n0 + colL];
#pragma unroll
        for (int r = 0; r < 4; r++) {
          const int rowL = wm + i * 16 + quad * 4 + r;
          SMEM[rowL * EPAD + colL] = f2bf(gelu_erf(acc[i][j][r] + bias));
        }
      }
    }
    __syncthreads();
    const int gg = tid & 15;
    const int rb = tid >> 4;
#pragma unroll
    for (int p = 0; p < 8; p++) {
      const int rowL = rb + p * 16;
      const ull2 v = *(const ull2*)&SMEM[rowL * EPAD + gg * 8];
      *(ull2*)&h[(size_t)(bt * BM + rowL) * DMLP + n0 + gg * 8] = v;
    }
  }

  // ---- tail: convert this block's share of W2 -> W2T (4096 chunks) -------
  const int fb = bt * gridDim.x + blockIdx.x;   // flat block id, 0..1279
#pragma unroll
  for (int r = 0; r < 4; r++) {
    const int c = fb + 1280 * r;
    if (c < 4096) {
      convpack_body(W2, W2T, DMLP, DIM, c & 511, 0, c >> 9, tid);
    }
  }
}

// ---------------------------------------------------------------------------
// Kernel 3: out[tok] += h @ W2 (partial), scatter via atomicAdd. SPLIT-K=2:
// grid (DIM/64, NTILES, 2) = 1280 blocks = exactly 5 blocks/CU at 48 KB LDS
// (3 resident) -- removes the 2.5/CU imbalance tail of the 640-block grid.
// Bias is pre-initialized in prep; each kh half adds its f32 partial.
// ---------------------------------------------------------------------------
__global__ __launch_bounds__(256)
void gemm2_kernel(const unsigned short* __restrict__ h,
                  const unsigned short* __restrict__ W2T,
                  const int* __restrict__ perm,
                  const int* __restrict__ tile_e, float* __restrict__ out) {
  const int bt = blockIdx.y;
  const int te = tile_e[bt];
  if (te < 0) return;
  const int kh = blockIdx.z;                 // 0/1: K half [kh*2048, +2048)
  const int n0 = blockIdx.x * BN2;
  const unsigned short* Asrc = h + (size_t)bt * BM * DMLP + kh * (DMLP / 2);
  const int tid = threadIdx.x;

  __shared__ __align__(16) unsigned short As[BM * BK];      // 32 KB
  __shared__ __align__(16) unsigned short Bs[16 * BN2 * 8]; // 16 KB [C][64][8]

  const int rr = tid >> 4, q = tid & 15;
  const int cs = SWZ(rr, q);
  const unsigned short* a0 = Asrc + (size_t)rr * DMLP + cs * 8;
  const int bC = tid >> 6, bn = tid & 63;
  const unsigned short* b0 = W2T + (size_t)te * DMLP * DIM
                           + ((size_t)(kh * (DMLP / 2) / 8 + bC) * DIM + n0 + bn) * 8;

  const int wid = tid >> 6, lane = tid & 63;
  const int wm = (wid >> 1) * 64, wn = (wid & 1) * 32;
  const int l15 = lane & 15, quad = lane >> 4;

  float4v acc[4][2];
#pragma unroll
  for (int i = 0; i < 4; i++)
#pragma unroll
    for (int j = 0; j < 2; j++) acc[i][j] = (float4v){0.f, 0.f, 0.f, 0.f};

  for (int k0 = 0; k0 < DMLP / 2; k0 += BK) {
    const int kg0 = k0 >> 3;
#pragma unroll
    for (int t = 0; t < 8; t++)
      ASYNC16(a0 + (size_t)(16 * t) * DMLP + k0, &As[(t * 256 + tid) * 8]);
#pragma unroll
    for (int t = 0; t < 4; t++)
      ASYNC16(b0 + (size_t)(kg0 + 4 * t) * DIM * 8, &Bs[(t * 256 + tid) * 8]);
    __syncthreads();

#pragma unroll
    for (int hh = 0; hh < 4; hh++) {
      short8 a[4], b[2];
      const int C = hh * 4 + quad;
#pragma unroll
      for (int i = 0; i < 4; i++)
        a[i] = *(const short8*)&As[FRAG_OFF(wm + i * 16 + l15, C)];
#pragma unroll
      for (int j = 0; j < 2; j++)
        b[j] = *(const short8*)&Bs[(((C) << 6) + wn + j * 16 + l15) << 3];
#pragma unroll
      for (int i = 0; i < 4; i++)
#pragma unroll
        for (int j = 0; j < 2; j++)
          acc[i][j] = __builtin_amdgcn_mfma_f32_16x16x32_bf16(a[i], b[j], acc[i][j], 0, 0, 0);
    }
    __syncthreads();
  }

#pragma unroll
  for (int i = 0; i < 4; i++) {
#pragma unroll
    for (int j = 0; j < 2; j++) {
      const int col = n0 + wn + j * 16 + l15;
#pragma unroll
      for (int r = 0; r < 4; r++) {
        const int row  = wm + i * 16 + quad * 4 + r;
        const int slot = bt * BM + row;
        const int t    = perm[slot];
        if (t >= 0) atomicAdd(&out[(size_t)t * DIM + col], acc[i][j][r]);
      }
    }
  }
}

// ---------------------------------------------------------------------------
extern "C" void kernel_launch(void* const* d_in, const int* in_sizes, int n_in,
                              void* d_out, int out_size, void* d_ws, size_t ws_size,
                              hipStream_t stream) {
  const float* x    = (const float*)d_in[0];
  const int*   eidx = (const int*)d_in[1];
  const float* W1   = (const float*)d_in[2];
  const float* b1   = (const float*)d_in[3];
  const float* W2   = (const float*)d_in[4];
  const float* b2   = (const float*)d_in[5];
  float* out = (float*)d_out;

  char* ws = (char*)d_ws;
  int* perm   = (int*)ws;                              // 5120 ints
  int* tile_e = (int*)(ws + PADMAX * sizeof(int));     // 40 ints
  unsigned short* xbf = (unsigned short*)(ws + 32768);                      // 8 MB
  unsigned short* h   = (unsigned short*)(ws + 32768 + 10485760);           // 40 MB
  unsigned short* W1T = (unsigned short*)(ws + 32768 + 10485760 + 41943040);// 64 MB
  unsigned short* W2T = (unsigned short*)((char*)W1T + 67108864);           // 64 MB

  prep_kernel<<<8193, 256, 0, stream>>>(eidx, perm, tile_e, W1, W1T, x, xbf, b2, out);
  gemm1_kernel<<<dim3(DMLP / BN, NTILES), 256, 0, stream>>>(xbf, W1T, b1, perm, tile_e, h, W2, W2T);
  gemm2_kernel<<<dim3(DIM / BN2, NTILES, 2), 256, 0, stream>>>(h, W2T, perm, tile_e, out);
}

// Round 17
// 448.170 us; speedup vs baseline: 1.0141x; 1.0141x over previous
//
#include <hip/hip_runtime.h>
#include <hip/hip_bf16.h>
#include <math.h>

#define TOK   4096
#define DIM   1024
#define DMLP  4096
#define NE    8
#define BM    128
#define BN    128
#define BN2   64
#define BK    128
#define PADMAX (TOK + NE * BM)   // 5120 padded slots
#define NTILES (PADMAX / BM)     // 40 row-tiles
#define EPAD  136                // epilogue LDS row stride (shorts), 16B-aligned

typedef __attribute__((ext_vector_type(8))) short  short8;
typedef __attribute__((ext_vector_type(4))) float  float4v;
typedef __attribute__((ext_vector_type(4))) unsigned short ushort4v;
typedef __attribute__((ext_vector_type(2))) unsigned long long ull2;

// async global->LDS, 16 B per lane; LDS dest is wave-uniform base + lane*16;
// GLOBAL source address is per-lane (enables the perm-gather A staging).
#define ASYNC16(gp, lp) __builtin_amdgcn_global_load_lds( \
    (const __attribute__((address_space(1))) unsigned int*)(gp), \
    (__attribute__((address_space(3))) unsigned int*)(lp), 16, 0, 0)

// A-side LDS layout (row-major, swizzled): BK=128 -> 16 granules/row
#define SWZ(R, C) (((C) & 8) | (((C) ^ (R)) & 7))
#define FRAG_OFF(R, C) ((((R) << 4) + SWZ(R, C)) << 3)
// B-side LDS layout (granule-major): [C][n][8], offset in shorts (n<128)
#define BOFF(C, n) ((((C) << 7) + (n)) << 3)

static __device__ __forceinline__ unsigned short f2bf(float f) {
  unsigned u = __float_as_uint(f);
  u += 0x7fffu + ((u >> 16) & 1u);
  return (unsigned short)(u >> 16);
}

// exact-erf GELU via Abramowitz&Stegun 7.1.26 (|err| < 1.5e-7)
static __device__ __forceinline__ float gelu_erf(float v) {
  const float x = fabsf(v) * 0.70710678118654752f;
  const float t = __builtin_amdgcn_rcpf(1.0f + 0.3275911f * x);
  const float poly = ((((1.061405429f * t - 1.453152027f) * t + 1.421413741f) * t
                       - 0.284496736f) * t + 0.254829592f) * t;
  const float erf_abs = 1.0f - poly * __expf(-x * x);
  return 0.5f * v * (1.0f + copysignf(erf_abs, v));
}

// ---------------------------------------------------------------------------
// group body (single block): token counts -> expert offsets -> perm/tile_e.
// ---------------------------------------------------------------------------
static __device__ __forceinline__
void group_body(const int* __restrict__ eidx, int* __restrict__ perm,
                int* __restrict__ tile_e, int tid) {
  __shared__ int cnt[NE], off[NE], len[NE], cur[NE];
  if (tid < NE) cnt[tid] = 0;
  __syncthreads();
  for (int i = tid; i < TOK; i += 256) atomicAdd(&cnt[eidx[i]], 1);
  __syncthreads();
  if (tid == 0) {
    int o = 0;
    for (int e = 0; e < NE; e++) {
      off[e] = o;
      len[e] = ((cnt[e] + BM - 1) / BM) * BM;
      cur[e] = o;
      o += len[e];
    }
  }
  __syncthreads();
  for (int s = tid; s < PADMAX; s += 256) perm[s] = -1;
  __syncthreads();
  for (int i = tid; i < TOK; i += 256) {
    const int e = eidx[i];
    const int p = atomicAdd(&cur[e], 1);
    perm[p] = i;
  }
  __syncthreads();
  for (int t = tid; t < NTILES; t += 256) {
    const int row = t * BM;
    int te = -1;
    for (int e = 0; e < NE; e++)
      if (row >= off[e] && row < off[e] + len[e]) te = e;
    tile_e[t] = te;
  }
}

// ---------------------------------------------------------------------------
// convpack body (r9 proven): W [K][N] f32 -> WT [K/8][N][8] bf16.
// ---------------------------------------------------------------------------
static __device__ __forceinline__
void convpack_body(const float* __restrict__ W, unsigned short* __restrict__ WT,
                   int K, int N, int kg, int nblk, int e, int tid) {
  const int n0 = nblk * 1024 + tid * 4;
  const float* Win = W + (size_t)e * K * N + (size_t)kg * 8 * N + n0;
  unsigned short* Wout = WT + (size_t)e * K * N + ((size_t)kg * N + n0) * 8;
  float4v v[8];
#pragma unroll
  for (int j = 0; j < 8; j++) v[j] = *(const float4v*)(Win + (size_t)j * N);
#pragma unroll
  for (int q = 0; q < 4; q++) {
    short8 g;
#pragma unroll
    for (int j = 0; j < 8; j++) g[j] = (short)f2bf(v[j][q]);
    *(short8*)(Wout + q * 8) = g;
  }
}

// ---------------------------------------------------------------------------
// Kernel 1 (prep): group (block 0) + convpack(W1) + x f32->bf16 TOKEN-ORDER.
// Blocks: [0]=group, [1,4097)=W1 conv, [4097,8193)=x rows. (r15 exact)
// ---------------------------------------------------------------------------
__global__ __launch_bounds__(256)
void prep_kernel(const int* __restrict__ eidx, int* __restrict__ perm,
                 int* __restrict__ tile_e,
                 const float* __restrict__ W1, unsigned short* __restrict__ W1T,
                 const float* __restrict__ x, unsigned short* __restrict__ xbf) {
  const int bid = blockIdx.x;
  const int tid = threadIdx.x;
  if (bid == 0) {
    group_body(eidx, perm, tile_e, tid);
  } else if (bid < 4097) {
    const int b = bid - 1;
    convpack_body(W1, W1T, DIM, DMLP, b & 127, (b >> 7) & 3, b >> 9, tid);
  } else {
    const int row = bid - 4097;           // 0..4095, token order
    const float4v v = *(const float4v*)(x + (size_t)row * DIM + tid * 4);
    ushort4v o;
#pragma unroll
    for (int q = 0; q < 4; q++) o[q] = f2bf(v[q]);
    *(ushort4v*)(xbf + (size_t)row * DIM + tid * 4) = o;
  }
}

// ---------------------------------------------------------------------------
// Kernel 2: h = gelu(x[perm] @ W1 + b1) -> bf16. 128x128 tile, BK=128.
// A staged directly from token-ordered xbf via per-lane perm-gathered global
// addresses. B granule-major. Padded epilogue restage. + W2 conv tail work.
// Grid: (DMLP/BN, NTILES) col-fastest. (r15 exact)
// ---------------------------------------------------------------------------
__global__ __launch_bounds__(256)
void gemm1_kernel(const unsigned short* __restrict__ xbf,
                  const unsigned short* __restrict__ W1T,
                  const float* __restrict__ b1, const int* __restrict__ perm,
                  const int* __restrict__ tile_e,
                  unsigned short* __restrict__ h,
                  const float* __restrict__ W2, unsigned short* __restrict__ W2T) {
  const int bt = blockIdx.y;                 // row tile
  const int te = tile_e[bt];
  const int n0 = blockIdx.x * BN;            // col tile
  const int tid = threadIdx.x;

  __shared__ __align__(16) unsigned short SMEM[2 * BM * BK];

  if (te >= 0) {
    const unsigned short* Bsrc = W1T + (size_t)te * DIM * DMLP + (size_t)n0 * 8;

    const int rr = tid >> 4, q = tid & 15;
    const int cs = SWZ(rr, q);
    const unsigned short* aP[8];
#pragma unroll
    for (int t = 0; t < 8; t++) {
      const int tok = perm[bt * BM + 16 * t + rr];
      aP[t] = xbf + (size_t)(tok < 0 ? 0 : tok) * DIM + cs * 8;
    }
    const int bC = tid >> 7, bn = tid & 127;   // t adds 2 to C per step
    const unsigned short* b0 = Bsrc + ((size_t)bC * DMLP + bn) * 8;

    const int wid = tid >> 6, lane = tid & 63;
    const int wm = (wid >> 1) * 64, wn = (wid & 1) * 64;
    const int l15 = lane & 15, quad = lane >> 4;

    float4v acc[4][4];
#pragma unroll
    for (int i = 0; i < 4; i++)
#pragma unroll
      for (int j = 0; j < 4; j++) acc[i][j] = (float4v){0.f, 0.f, 0.f, 0.f};

    for (int k0 = 0; k0 < DIM; k0 += BK) {
      const int kg0 = k0 >> 3;
#pragma unroll
      for (int t = 0; t < 8; t++)
        ASYNC16(aP[t] + k0, &SMEM[(t * 256 + tid) * 8]);
#pragma unroll
      for (int t = 0; t < 8; t++)
        ASYNC16(b0 + (size_t)(kg0 + 2 * t) * DMLP * 8,
                &SMEM[BM * BK + (t * 256 + tid) * 8]);
      __syncthreads();

#pragma unroll
      for (int hh = 0; hh < 4; hh++) {
        short8 a[4], b[4];
        const int C = hh * 4 + quad;
#pragma unroll
        for (int i = 0; i < 4; i++)
          a[i] = *(const short8*)&SMEM[FRAG_OFF(wm + i * 16 + l15, C)];
#pragma unroll
        for (int j = 0; j < 4; j++)
          b[j] = *(const short8*)&SMEM[BM * BK + BOFF(C, wn + j * 16 + l15)];
#pragma unroll
        for (int i = 0; i < 4; i++)
#pragma unroll
          for (int j = 0; j < 4; j++)
            acc[i][j] = __builtin_amdgcn_mfma_f32_16x16x32_bf16(a[i], b[j], acc[i][j], 0, 0, 0);
      }
      __syncthreads();
    }

    // ---- epilogue: gelu -> bf16 into padded LDS tile, then wide stores ----
#pragma unroll
    for (int i = 0; i < 4; i++) {
#pragma unroll
      for (int j = 0; j < 4; j++) {
        const int colL = wn + j * 16 + l15;
        const float bias = b1[te * DMLP + n0 + colL];
#pragma unroll
        for (int r = 0; r < 4; r++) {
          const int rowL = wm + i * 16 + quad * 4 + r;
          SMEM[rowL * EPAD + colL] = f2bf(gelu_erf(acc[i][j][r] + bias));
        }
      }
    }
    __syncthreads();
    const int gg = tid & 15;
    const int rb = tid >> 4;
#pragma unroll
    for (int p = 0; p < 8; p++) {
      const int rowL = rb + p * 16;
      const ull2 v = *(const ull2*)&SMEM[rowL * EPAD + gg * 8];
      *(ull2*)&h[(size_t)(bt * BM + rowL) * DMLP + n0 + gg * 8] = v;
    }
  }

  // ---- tail: convert this block's share of W2 -> W2T (4096 chunks) -------
  const int fb = bt * gridDim.x + blockIdx.x;   // flat block id, 0..1279
#pragma unroll
  for (int r = 0; r < 4; r++) {
    const int c = fb + 1280 * r;
    if (c < 4096) {
      convpack_body(W2, W2T, DMLP, DIM, c & 511, 0, c >> 9, tid);
    }
  }
}

// ---------------------------------------------------------------------------
// Kernel 3: out[tok] = h @ W2 + b2, scatter. 128x64 tile, BK=128, direct
// stores (r15 exact math) + XCD-CHUNKED BLOCK SWIZZLE: 640 blocks = 8 x 80
// exactly, each XCD owns a compact 5-row-tile x 16-col-tile region so its
// h A-panels (1 MB each) are fetched once into the XCD-local L2 instead of
// 8 copies across XCDs. Bijective (640 % 8 == 0).
// Grid: (DIM/64, NTILES).
// ---------------------------------------------------------------------------
__global__ __launch_bounds__(256)
void gemm2_kernel(const unsigned short* __restrict__ h,
                  const unsigned short* __restrict__ W2T,
                  const float* __restrict__ b2, const int* __restrict__ perm,
                  const int* __restrict__ tile_e, float* __restrict__ out) {
  // XCD-chunked swizzle of the flat block id
  const int bid = blockIdx.y * gridDim.x + blockIdx.x;   // 0..639
  const int nb  = (bid & 7) * 80 + (bid >> 3);           // bijective remap
  const int bt  = nb >> 4;                               // row tile 0..39
  const int bx  = nb & 15;                               // col tile 0..15

  const int te = tile_e[bt];
  if (te < 0) return;
  const int n0 = bx * BN2;
  const unsigned short* Asrc = h + (size_t)bt * BM * DMLP;
  const int tid = threadIdx.x;

  __shared__ __align__(16) unsigned short As[BM * BK];      // 32 KB
  __shared__ __align__(16) unsigned short Bs[16 * BN2 * 8]; // 16 KB [C][64][8]

  const int rr = tid >> 4, q = tid & 15;
  const int cs = SWZ(rr, q);
  const unsigned short* a0 = Asrc + (size_t)rr * DMLP + cs * 8;
  const int bC = tid >> 6, bn = tid & 63;
  const unsigned short* b0 = W2T + (size_t)te * DMLP * DIM
                           + ((size_t)bC * DIM + n0 + bn) * 8;

  const int wid = tid >> 6, lane = tid & 63;
  const int wm = (wid >> 1) * 64, wn = (wid & 1) * 32;
  const int l15 = lane & 15, quad = lane >> 4;

  float4v acc[4][2];
#pragma unroll
  for (int i = 0; i < 4; i++)
#pragma unroll
    for (int j = 0; j < 2; j++) acc[i][j] = (float4v){0.f, 0.f, 0.f, 0.f};

  for (int k0 = 0; k0 < DMLP; k0 += BK) {
    const int kg0 = k0 >> 3;
#pragma unroll
    for (int t = 0; t < 8; t++)
      ASYNC16(a0 + (size_t)(16 * t) * DMLP + k0, &As[(t * 256 + tid) * 8]);
#pragma unroll
    for (int t = 0; t < 4; t++)
      ASYNC16(b0 + (size_t)(kg0 + 4 * t) * DIM * 8, &Bs[(t * 256 + tid) * 8]);
    __syncthreads();

#pragma unroll
    for (int hh = 0; hh < 4; hh++) {
      short8 a[4], b[2];
      const int C = hh * 4 + quad;
#pragma unroll
      for (int i = 0; i < 4; i++)
        a[i] = *(const short8*)&As[FRAG_OFF(wm + i * 16 + l15, C)];
#pragma unroll
      for (int j = 0; j < 2; j++)
        b[j] = *(const short8*)&Bs[(((C) << 6) + wn + j * 16 + l15) << 3];
#pragma unroll
      for (int i = 0; i < 4; i++)
#pragma unroll
        for (int j = 0; j < 2; j++)
          acc[i][j] = __builtin_amdgcn_mfma_f32_16x16x32_bf16(a[i], b[j], acc[i][j], 0, 0, 0);
    }
    __syncthreads();
  }

#pragma unroll
  for (int i = 0; i < 4; i++) {
#pragma unroll
    for (int j = 0; j < 2; j++) {
      const int col = n0 + wn + j * 16 + l15;
      const float bias = b2[te * DIM + col];
#pragma unroll
      for (int r = 0; r < 4; r++) {
        const int row  = wm + i * 16 + quad * 4 + r;
        const int slot = bt * BM + row;
        const int t    = perm[slot];
        if (t >= 0) out[(size_t)t * DIM + col] = acc[i][j][r] + bias;
      }
    }
  }
}

// ---------------------------------------------------------------------------
extern "C" void kernel_launch(void* const* d_in, const int* in_sizes, int n_in,
                              void* d_out, int out_size, void* d_ws, size_t ws_size,
                              hipStream_t stream) {
  const float* x    = (const float*)d_in[0];
  const int*   eidx = (const int*)d_in[1];
  const float* W1   = (const float*)d_in[2];
  const float* b1   = (const float*)d_in[3];
  const float* W2   = (const float*)d_in[4];
  const float* b2   = (const float*)d_in[5];
  float* out = (float*)d_out;

  char* ws = (char*)d_ws;
  int* perm   = (int*)ws;                              // 5120 ints
  int* tile_e = (int*)(ws + PADMAX * sizeof(int));     // 40 ints
  unsigned short* xbf = (unsigned short*)(ws + 32768);                      // 8 MB
  unsigned short* h   = (unsigned short*)(ws + 32768 + 10485760);           // 40 MB
  unsigned short* W1T = (unsigned short*)(ws + 32768 + 10485760 + 41943040);// 64 MB
  unsigned short* W2T = (unsigned short*)((char*)W1T + 67108864);           // 64 MB

  prep_kernel<<<8193, 256, 0, stream>>>(eidx, perm, tile_e, W1, W1T, x, xbf);
  gemm1_kernel<<<dim3(DMLP / BN, NTILES), 256, 0, stream>>>(xbf, W1T, b1, perm, tile_e, h, W2, W2T);
  gemm2_kernel<<<dim3(DIM / BN2, NTILES), 256, 0, stream>>>(h, W2T, b2, perm, tile_e, out);
}

// Round 18
// 445.151 us; speedup vs baseline: 1.0209x; 1.0068x over previous
//
#include <hip/hip_runtime.h>
#include <hip/hip_bf16.h>
#include <math.h>

#define TOK   4096
#define DIM   1024
#define DMLP  4096
#define NE    8
#define BM    128
#define BN    128
#define BN2   64
#define BK    128
#define PADMAX (TOK + NE * BM)   // 5120 padded slots
#define NTILES (PADMAX / BM)     // 40 row-tiles
#define EPAD  136                // epilogue LDS row stride (shorts), 16B-aligned

typedef __attribute__((ext_vector_type(8))) short  short8;
typedef __attribute__((ext_vector_type(4))) float  float4v;
typedef __attribute__((ext_vector_type(4))) unsigned short ushort4v;
typedef __attribute__((ext_vector_type(2))) unsigned long long ull2;

// async global->LDS, 16 B per lane; LDS dest is wave-uniform base + lane*16;
// GLOBAL source address is per-lane (enables the perm-gather A staging).
#define ASYNC16(gp, lp) __builtin_amdgcn_global_load_lds( \
    (const __attribute__((address_space(1))) unsigned int*)(gp), \
    (__attribute__((address_space(3))) unsigned int*)(lp), 16, 0, 0)

// A-side LDS layout (row-major, swizzled): BK=128 -> 16 granules/row
#define SWZ(R, C) (((C) & 8) | (((C) ^ (R)) & 7))
#define FRAG_OFF(R, C) ((((R) << 4) + SWZ(R, C)) << 3)
// B-side LDS layout (granule-major): [C][n][8], offset in shorts (n<128)
#define BOFF(C, n) ((((C) << 7) + (n)) << 3)

static __device__ __forceinline__ unsigned short f2bf(float f) {
  unsigned u = __float_as_uint(f);
  u += 0x7fffu + ((u >> 16) & 1u);
  return (unsigned short)(u >> 16);
}

// exact-erf GELU via Abramowitz&Stegun 7.1.26 (|err| < 1.5e-7)
static __device__ __forceinline__ float gelu_erf(float v) {
  const float x = fabsf(v) * 0.70710678118654752f;
  const float t = __builtin_amdgcn_rcpf(1.0f + 0.3275911f * x);
  const float poly = ((((1.061405429f * t - 1.453152027f) * t + 1.421413741f) * t
                       - 0.284496736f) * t + 0.254829592f) * t;
  const float erf_abs = 1.0f - poly * __expf(-x * x);
  return 0.5f * v * (1.0f + copysignf(erf_abs, v));
}

// ---------------------------------------------------------------------------
// group body (single block): token counts -> expert offsets -> perm/tile_e.
// ---------------------------------------------------------------------------
static __device__ __forceinline__
void group_body(const int* __restrict__ eidx, int* __restrict__ perm,
                int* __restrict__ tile_e, int tid) {
  __shared__ int cnt[NE], off[NE], len[NE], cur[NE];
  if (tid < NE) cnt[tid] = 0;
  __syncthreads();
  for (int i = tid; i < TOK; i += 256) atomicAdd(&cnt[eidx[i]], 1);
  __syncthreads();
  if (tid == 0) {
    int o = 0;
    for (int e = 0; e < NE; e++) {
      off[e] = o;
      len[e] = ((cnt[e] + BM - 1) / BM) * BM;
      cur[e] = o;
      o += len[e];
    }
  }
  __syncthreads();
  for (int s = tid; s < PADMAX; s += 256) perm[s] = -1;
  __syncthreads();
  for (int i = tid; i < TOK; i += 256) {
    const int e = eidx[i];
    const int p = atomicAdd(&cur[e], 1);
    perm[p] = i;
  }
  __syncthreads();
  for (int t = tid; t < NTILES; t += 256) {
    const int row = t * BM;
    int te = -1;
    for (int e = 0; e < NE; e++)
      if (row >= off[e] && row < off[e] + len[e]) te = e;
    tile_e[t] = te;
  }
}

// ---------------------------------------------------------------------------
// convpack body (r9 proven): W [K][N] f32 -> WT [K/8][N][8] bf16.
// ---------------------------------------------------------------------------
static __device__ __forceinline__
void convpack_body(const float* __restrict__ W, unsigned short* __restrict__ WT,
                   int K, int N, int kg, int nblk, int e, int tid) {
  const int n0 = nblk * 1024 + tid * 4;
  const float* Win = W + (size_t)e * K * N + (size_t)kg * 8 * N + n0;
  unsigned short* Wout = WT + (size_t)e * K * N + ((size_t)kg * N + n0) * 8;
  float4v v[8];
#pragma unroll
  for (int j = 0; j < 8; j++) v[j] = *(const float4v*)(Win + (size_t)j * N);
#pragma unroll
  for (int q = 0; q < 4; q++) {
    short8 g;
#pragma unroll
    for (int j = 0; j < 8; j++) g[j] = (short)f2bf(v[j][q]);
    *(short8*)(Wout + q * 8) = g;
  }
}

// ---------------------------------------------------------------------------
// Kernel 1 (prep): group (block 0) + convpack(W1) + x f32->bf16 TOKEN-ORDER.
// No intra-kernel dependencies: perm/tile_e are consumed only by the next
// launch; x-convert needs no perm (gemm1 gathers via per-lane ASYNC16 src).
// Blocks: [0]=group, [1,4097)=W1 conv, [4097,8193)=x rows.
// ---------------------------------------------------------------------------
__global__ __launch_bounds__(256)
void prep_kernel(const int* __restrict__ eidx, int* __restrict__ perm,
                 int* __restrict__ tile_e,
                 const float* __restrict__ W1, unsigned short* __restrict__ W1T,
                 const float* __restrict__ x, unsigned short* __restrict__ xbf) {
  const int bid = blockIdx.x;
  const int tid = threadIdx.x;
  if (bid == 0) {
    group_body(eidx, perm, tile_e, tid);
  } else if (bid < 4097) {
    const int b = bid - 1;
    convpack_body(W1, W1T, DIM, DMLP, b & 127, (b >> 7) & 3, b >> 9, tid);
  } else {
    const int row = bid - 4097;           // 0..4095, token order
    const float4v v = *(const float4v*)(x + (size_t)row * DIM + tid * 4);
    ushort4v o;
#pragma unroll
    for (int q = 0; q < 4; q++) o[q] = f2bf(v[q]);
    *(ushort4v*)(xbf + (size_t)row * DIM + tid * 4) = o;
  }
}

// ---------------------------------------------------------------------------
// Kernel 2: h = gelu(x[perm] @ W1 + b1) -> bf16. 128x128 tile, BK=128.
// A staged DIRECTLY from token-ordered xbf via per-lane perm-gathered global
// addresses (deletes the xgather pass). B granule-major (r9). Epilogue LDS
// restage padded to stride 136. + W2 conv tail work.
// Grid: (DMLP/BN, NTILES) col-fastest.
// ---------------------------------------------------------------------------
__global__ __launch_bounds__(256)
void gemm1_kernel(const unsigned short* __restrict__ xbf,
                  const unsigned short* __restrict__ W1T,
                  const float* __restrict__ b1, const int* __restrict__ perm,
                  const int* __restrict__ tile_e,
                  unsigned short* __restrict__ h,
                  const float* __restrict__ W2, unsigned short* __restrict__ W2T) {
  const int bt = blockIdx.y;                 // row tile
  const int te = tile_e[bt];
  const int n0 = blockIdx.x * BN;            // col tile
  const int tid = threadIdx.x;

  __shared__ __align__(16) unsigned short SMEM[2 * BM * BK];

  if (te >= 0) {
    const unsigned short* Bsrc = W1T + (size_t)te * DIM * DMLP + (size_t)n0 * 8;

    const int rr = tid >> 4, q = tid & 15;
    const int cs = SWZ(rr, q);
    const unsigned short* aP[8];
#pragma unroll
    for (int t = 0; t < 8; t++) {
      const int tok = perm[bt * BM + 16 * t + rr];
      aP[t] = xbf + (size_t)(tok < 0 ? 0 : tok) * DIM + cs * 8;
    }
    const int bC = tid >> 7, bn = tid & 127;   // t adds 2 to C per step
    const unsigned short* b0 = Bsrc + ((size_t)bC * DMLP + bn) * 8;

    const int wid = tid >> 6, lane = tid & 63;
    const int wm = (wid >> 1) * 64, wn = (wid & 1) * 64;
    const int l15 = lane & 15, quad = lane >> 4;

    float4v acc[4][4];
#pragma unroll
    for (int i = 0; i < 4; i++)
#pragma unroll
      for (int j = 0; j < 4; j++) acc[i][j] = (float4v){0.f, 0.f, 0.f, 0.f};

    for (int k0 = 0; k0 < DIM; k0 += BK) {
      const int kg0 = k0 >> 3;
#pragma unroll
      for (int t = 0; t < 8; t++)
        ASYNC16(aP[t] + k0, &SMEM[(t * 256 + tid) * 8]);
#pragma unroll
      for (int t = 0; t < 8; t++)
        ASYNC16(b0 + (size_t)(kg0 + 2 * t) * DMLP * 8,
                &SMEM[BM * BK + (t * 256 + tid) * 8]);
      __syncthreads();

#pragma unroll
      for (int hh = 0; hh < 4; hh++) {
        short8 a[4], b[4];
        const int C = hh * 4 + quad;
#pragma unroll
        for (int i = 0; i < 4; i++)
          a[i] = *(const short8*)&SMEM[FRAG_OFF(wm + i * 16 + l15, C)];
#pragma unroll
        for (int j = 0; j < 4; j++)
          b[j] = *(const short8*)&SMEM[BM * BK + BOFF(C, wn + j * 16 + l15)];
#pragma unroll
        for (int i = 0; i < 4; i++)
#pragma unroll
          for (int j = 0; j < 4; j++)
            acc[i][j] = __builtin_amdgcn_mfma_f32_16x16x32_bf16(a[i], b[j], acc[i][j], 0, 0, 0);
      }
      __syncthreads();
    }

    // ---- epilogue: gelu -> bf16 into padded LDS tile, then wide stores ----
#pragma unroll
    for (int i = 0; i < 4; i++) {
#pragma unroll
      for (int j = 0; j < 4; j++) {
        const int colL = wn + j * 16 + l15;
        const float bias = b1[te * DMLP + n0 + colL];
#pragma unroll
        for (int r = 0; r < 4; r++) {
          const int rowL = wm + i * 16 + quad * 4 + r;
          SMEM[rowL * EPAD + colL] = f2bf(gelu_erf(acc[i][j][r] + bias));
        }
      }
    }
    __syncthreads();
    const int gg = tid & 15;
    const int rb = tid >> 4;
#pragma unroll
    for (int p = 0; p < 8; p++) {
      const int rowL = rb + p * 16;
      const ull2 v = *(const ull2*)&SMEM[rowL * EPAD + gg * 8];
      *(ull2*)&h[(size_t)(bt * BM + rowL) * DMLP + n0 + gg * 8] = v;
    }
  }

  // ---- tail: convert this block's share of W2 -> W2T (4096 chunks) -------
  const int fb = bt * gridDim.x + blockIdx.x;   // flat block id, 0..1279
#pragma unroll
  for (int r = 0; r < 4; r++) {
    const int c = fb + 1280 * r;
    if (c < 4096) {
      convpack_body(W2, W2T, DMLP, DIM, c & 511, 0, c >> 9, tid);
    }
  }
}

// ---------------------------------------------------------------------------
// Kernel 3: out[tok] = h @ W2 + b2, scatter. 128x64 tile, BK=128 (48 KB LDS
// -> 3 blocks/CU, 640 blocks, granule-major B, conflict-free, direct store).
// Grid: (DIM/64, NTILES) col-fastest.
// ---------------------------------------------------------------------------
__global__ __launch_bounds__(256)
void gemm2_kernel(const unsigned short* __restrict__ h,
                  const unsigned short* __restrict__ W2T,
                  const float* __restrict__ b2, const int* __restrict__ perm,
                  const int* __restrict__ tile_e, float* __restrict__ out) {
  const int bt = blockIdx.y;
  const int te = tile_e[bt];
  if (te < 0) return;
  const int n0 = blockIdx.x * BN2;
  const unsigned short* Asrc = h + (size_t)bt * BM * DMLP;
  const int tid = threadIdx.x;

  __shared__ __align__(16) unsigned short As[BM * BK];      // 32 KB
  __shared__ __align__(16) unsigned short Bs[16 * BN2 * 8]; // 16 KB [C][64][8]

  const int rr = tid >> 4, q = tid & 15;
  const int cs = SWZ(rr, q);
  const unsigned short* a0 = Asrc + (size_t)rr * DMLP + cs * 8;
  const int bC = tid >> 6, bn = tid & 63;
  const unsigned short* b0 = W2T + (size_t)te * DMLP * DIM
                           + ((size_t)bC * DIM + n0 + bn) * 8;

  const int wid = tid >> 6, lane = tid & 63;
  const int wm = (wid >> 1) * 64, wn = (wid & 1) * 32;
  const int l15 = lane & 15, quad = lane >> 4;

  float4v acc[4][2];
#pragma unroll
  for (int i = 0; i < 4; i++)
#pragma unroll
    for (int j = 0; j < 2; j++) acc[i][j] = (float4v){0.f, 0.f, 0.f, 0.f};

  for (int k0 = 0; k0 < DMLP; k0 += BK) {
    const int kg0 = k0 >> 3;
#pragma unroll
    for (int t = 0; t < 8; t++)
      ASYNC16(a0 + (size_t)(16 * t) * DMLP + k0, &As[(t * 256 + tid) * 8]);
#pragma unroll
    for (int t = 0; t < 4; t++)
      ASYNC16(b0 + (size_t)(kg0 + 4 * t) * DIM * 8, &Bs[(t * 256 + tid) * 8]);
    __syncthreads();

#pragma unroll
    for (int hh = 0; hh < 4; hh++) {
      short8 a[4], b[2];
      const int C = hh * 4 + quad;
#pragma unroll
      for (int i = 0; i < 4; i++)
        a[i] = *(const short8*)&As[FRAG_OFF(wm + i * 16 + l15, C)];
#pragma unroll
      for (int j = 0; j < 2; j++)
        b[j] = *(const short8*)&Bs[(((C) << 6) + wn + j * 16 + l15) << 3];
#pragma unroll
      for (int i = 0; i < 4; i++)
#pragma unroll
        for (int j = 0; j < 2; j++)
          acc[i][j] = __builtin_amdgcn_mfma_f32_16x16x32_bf16(a[i], b[j], acc[i][j], 0, 0, 0);
    }
    __syncthreads();
  }

#pragma unroll
  for (int i = 0; i < 4; i++) {
#pragma unroll
    for (int j = 0; j < 2; j++) {
      const int col = n0 + wn + j * 16 + l15;
      const float bias = b2[te * DIM + col];
#pragma unroll
      for (int r = 0; r < 4; r++) {
        const int row  = wm + i * 16 + quad * 4 + r;
        const int slot = bt * BM + row;
        const int t    = perm[slot];
        if (t >= 0) out[(size_t)t * DIM + col] = acc[i][j][r] + bias;
      }
    }
  }
}

// ---------------------------------------------------------------------------
extern "C" void kernel_launch(void* const* d_in, const int* in_sizes, int n_in,
                              void* d_out, int out_size, void* d_ws, size_t ws_size,
                              hipStream_t stream) {
  const float* x    = (const float*)d_in[0];
  const int*   eidx = (const int*)d_in[1];
  const float* W1   = (const float*)d_in[2];
  const float* b1   = (const float*)d_in[3];
  const float* W2   = (const float*)d_in[4];
  const float* b2   = (const float*)d_in[5];
  float* out = (float*)d_out;

  char* ws = (char*)d_ws;
  int* perm   = (int*)ws;                              // 5120 ints
  int* tile_e = (int*)(ws + PADMAX * sizeof(int));     // 40 ints
  unsigned short* xbf = (unsigned short*)(ws + 32768);                      // 8 MB
  unsigned short* h   = (unsigned short*)(ws + 32768 + 10485760);           // 40 MB
  unsigned short* W1T = (unsigned short*)(ws + 32768 + 10485760 + 41943040);// 64 MB
  unsigned short* W2T = (unsigned short*)((char*)W1T + 67108864);           // 64 MB

  prep_kernel<<<8193, 256, 0, stream>>>(eidx, perm, tile_e, W1, W1T, x, xbf);
  gemm1_kernel<<<dim3(DMLP / BN, NTILES), 256, 0, stream>>>(xbf, W1T, b1, perm, tile_e, h, W2, W2T);
  gemm2_kernel<<<dim3(DIM / BN2, NTILES), 256, 0, stream>>>(h, W2T, b2, perm, tile_e, out);
}